// Round 4
// baseline (525.943 us; speedup 1.0000x reference)
//
#include <hip/hip_runtime.h>
#include <cstddef>
#include <cstdint>

// LinearAttention B=4,S=4096,D=1024,H=16,Hd=64.  M=16384.
// Round 6: branch-free compile-time-unrolled K-loop for the 256x256 core.
//  - mfma256_core: prologue / main loop (2 K-tiles per iter, literal buffer
//    indices, zero conditionals) / explicit epilogue (T=14,15) with corrected
//    vmcnt(0) coverage.  Same phase schedule as R3 (proven safe).
//  - y_mfma: reverted to direct-store epilogue (R2 form; R3 staging cost ~10us).
//  - kv_ksum / reduce / cast / transpose unchanged.

typedef __attribute__((ext_vector_type(8))) __bf16 bf16x8;
typedef __attribute__((ext_vector_type(4))) __bf16 bf16x4;
typedef __attribute__((ext_vector_type(2))) __bf16 bf16x2;
typedef __attribute__((ext_vector_type(4))) float f32x4;

__device__ __forceinline__ void async_cp16(const void* g, void* s) {
    __builtin_amdgcn_global_load_lds(
        (__attribute__((address_space(1))) void*)g,
        (__attribute__((address_space(3))) void*)s, 16, 0, 0);
}

// ---------------------------------------------------------------------------
// 256x256 C-tile of A[.,1024]_bf16 x BT[1024,1024]_bf16^T, K=1024, BK=64.
// 512 threads = 8 waves (2M x 4N), per-wave 128x64 output.
// LDS: 2 buffers x (A 256x64 + B 256x64) bf16 = 128 KiB (dynamic).
// Swizzle: k-chunk (slot ^ (row&7)) via pre-swizzled global source (LDS dest
// linear) and XOR'd ds_read column; the XOR operand is a per-lane constant,
// so every ds_read folds to base-register + immediate offset.
//
// Per K-tile T (buffer BC=T&1 literal, BN=BC^1), one barrier per phase:
//   p0: reads aR1(T),bC1(T)[BC]; stage Bh1(T+1)->BN | MFMA r0c0(aR0,bC0)
//   p1: vmcnt(4);                stage Ah0(T+2)->BC | MFMA r0c1(aR0,bC1)
//   p2: vmcnt(2); reads aR0(T+1)[BN]; stage Ah1(T+2)| MFMA r1c0(aR1,bC0)
//   p3: reads bC0(T+1)[BN];      stage Bh0(T+2)->BC | MFMA r1c1(aR1,bC1)
// Each phase ends lgkmcnt(0); s_barrier (cross-wave write-after-read guard).
// Covering waits (vs load FIFO, 2 loads per staged half, verified):
//   vmcnt(4)@p1(T) retires Ah0/Ah1(T+1)  (read at p2(T), barrier between)
//   vmcnt(2)@p2(T) retires Bh0/Bh1(T+1)  (read at p3(T)/p0(T+1), barrier betw.)
// Epilogue: T=14 uses vmcnt(0)@p2 (no Ah0(16) in queue, so vmcnt(2) would
// leave Bh1(15) uncovered — latent race in R3, fixed here); T=15 no waits.
// ---------------------------------------------------------------------------

#define QUAD(ARR, BRR, RO, CO)                                                 \
    _Pragma("unroll")                                                          \
    for (int _qi = 0; _qi < 4; ++_qi)                                          \
        _Pragma("unroll")                                                      \
        for (int _qj = 0; _qj < 2; ++_qj)                                      \
            _Pragma("unroll")                                                  \
            for (int _qk = 0; _qk < 2; ++_qk)                                  \
                acc[(RO) + _qi][(CO) + _qj] =                                  \
                    __builtin_amdgcn_mfma_f32_16x16x32_bf16(                   \
                        ARR[_qi][_qk], BRR[_qj][_qk],                          \
                        acc[(RO) + _qi][(CO) + _qj], 0, 0, 0);

__device__ __forceinline__ void mfma256_core(const __bf16* __restrict__ A,
                                             const __bf16* __restrict__ BT,
                                             int mbase, int nbase,
                                             f32x4 acc[8][4])
{
    extern __shared__ __bf16 lds[];
    const int t    = threadIdx.x;
    const int lane = t & 63;
    const int wid  = t >> 6;                     // 0..7
    const int wm   = wid >> 2;                   // 0..1
    const int wn   = wid & 3;                    // 0..3
    const int fr   = lane & 15;
    const int fq   = lane >> 4;
    const int srow  = lane >> 3;                 // 0..7
    const int sslot = ((lane & 7) ^ srow) << 3;  // pre-swizzled k-chunk (elems)

    const __bf16* aBase = A  + (size_t)mbase * 1024;
    const __bf16* bBase = BT + (size_t)nbase * 1024;

#define STAGE_AH(tile, hh, bb)                                                 \
    { _Pragma("unroll") for (int _i = 0; _i < 2; ++_i) {                       \
          const int _c = 2 * wid + _i;                                         \
          async_cp16(aBase + (size_t)((hh) * 128 + _c * 8 + srow) * 1024       \
                         + (tile) * 64 + sslot,                                \
                     lds + (bb) * 32768 + (hh) * 8192 + _c * 512); } }
#define STAGE_BH(tile, hh, bb)                                                 \
    { _Pragma("unroll") for (int _i = 0; _i < 2; ++_i) {                       \
          const int _c = 2 * wid + _i;                                         \
          async_cp16(bBase + (size_t)((hh) * 128 + _c * 8 + srow) * 1024       \
                         + (tile) * 64 + sslot,                                \
                     lds + (bb) * 32768 + 16384 + (hh) * 8192 + _c * 512); } }
#define LDA(ri, ks, b)                                                         \
    (*(const bf16x8*)(lds + (b) * 32768 + (wm * 128 + (ri) * 16 + fr) * 64     \
                      + (((ks) * 32 + fq * 8) ^ ((fr & 7) << 3))))
#define LDB(cj, ks, b)                                                         \
    (*(const bf16x8*)(lds + (b) * 32768 + 16384                                \
                      + (wn * 64 + (cj) * 16 + fr) * 64                        \
                      + (((ks) * 32 + fq * 8) ^ ((fr & 7) << 3))))

#define PHASE_END                                                              \
    asm volatile("s_waitcnt lgkmcnt(0)" ::: "memory");                         \
    __builtin_amdgcn_s_barrier();

// One K-tile: BC/BN literal 0/1; DO_S2: stage tile T+2; DO_NX: tile T+1
// exists (reads of T+1, stage Bh1(T+1), waits).  P2W: vmcnt imm at p2.
#define KTILE(T, BC, BN, DO_S2, DO_NX, P2W)                                    \
    {                                                                          \
        /* ---- p0 ---- */                                                     \
        _Pragma("unroll") for (int _i = 0; _i < 4; ++_i)                       \
        _Pragma("unroll") for (int _ks = 0; _ks < 2; ++_ks)                    \
            aR1[_i][_ks] = LDA(4 + _i, _ks, BC);                               \
        _Pragma("unroll") for (int _j = 0; _j < 2; ++_j)                       \
        _Pragma("unroll") for (int _ks = 0; _ks < 2; ++_ks)                    \
            bC1[_j][_ks] = LDB(2 + _j, _ks, BC);                               \
        if (DO_NX) STAGE_BH((T) + 1, 1, BN)                                    \
        __builtin_amdgcn_sched_barrier(0);                                     \
        __builtin_amdgcn_s_setprio(1);                                         \
        QUAD(aR0, bC0, 0, 0)                                                   \
        __builtin_amdgcn_s_setprio(0);                                         \
        PHASE_END                                                              \
        /* ---- p1 ---- */                                                     \
        if (DO_NX) asm volatile("s_waitcnt vmcnt(4)" ::: "memory");            \
        if (DO_S2) STAGE_AH((T) + 2, 0, BC)                                    \
        __builtin_amdgcn_sched_barrier(0);                                     \
        __builtin_amdgcn_s_setprio(1);                                         \
        QUAD(aR0, bC1, 0, 2)                                                   \
        __builtin_amdgcn_s_setprio(0);                                         \
        PHASE_END                                                              \
        /* ---- p2 ---- */                                                     \
        if (DO_NX) asm volatile("s_waitcnt vmcnt(" P2W ")" ::: "memory");      \
        if (DO_NX) {                                                           \
            _Pragma("unroll") for (int _i = 0; _i < 4; ++_i)                   \
            _Pragma("unroll") for (int _ks = 0; _ks < 2; ++_ks)                \
                aR0[_i][_ks] = LDA(_i, _ks, BN);                               \
        }                                                                      \
        if (DO_S2) STAGE_AH((T) + 2, 1, BC)                                    \
        __builtin_amdgcn_sched_barrier(0);                                     \
        __builtin_amdgcn_s_setprio(1);                                         \
        QUAD(aR1, bC0, 4, 0)                                                   \
        __builtin_amdgcn_s_setprio(0);                                         \
        PHASE_END                                                              \
        /* ---- p3 ---- */                                                     \
        if (DO_NX) {                                                           \
            _Pragma("unroll") for (int _j = 0; _j < 2; ++_j)                   \
            _Pragma("unroll") for (int _ks = 0; _ks < 2; ++_ks)                \
                bC0[_j][_ks] = LDB(_j, _ks, BN);                               \
        }                                                                      \
        if (DO_S2) STAGE_BH((T) + 2, 0, BC)                                    \
        __builtin_amdgcn_sched_barrier(0);                                     \
        __builtin_amdgcn_s_setprio(1);                                         \
        QUAD(aR1, bC1, 4, 2)                                                   \
        __builtin_amdgcn_s_setprio(0);                                         \
        PHASE_END                                                              \
    }

    bf16x8 aR0[4][2], aR1[4][2], bC0[2][2], bC1[2][2];

    // prologue: tile0 fully + tile1 A-halves + Bh0(1); Bh1(1) staged at p0(0).
    STAGE_AH(0, 0, 0) STAGE_AH(0, 1, 0) STAGE_BH(0, 0, 0) STAGE_BH(0, 1, 0)
    STAGE_AH(1, 0, 1) STAGE_AH(1, 1, 1) STAGE_BH(1, 0, 1)
    asm volatile("s_waitcnt vmcnt(6)" ::: "memory");   // tile0's 8 retired
    __builtin_amdgcn_s_barrier();

#pragma unroll
    for (int i = 0; i < 4; ++i)
#pragma unroll
        for (int ks = 0; ks < 2; ++ks) aR0[i][ks] = LDA(i, ks, 0);
#pragma unroll
    for (int j = 0; j < 2; ++j)
#pragma unroll
        for (int ks = 0; ks < 2; ++ks) bC0[j][ks] = LDB(j, ks, 0);

    // main loop: tiles 0..13, branch-free, literal buffer indices.
    for (int T = 0; T < 14; T += 2) {
        KTILE(T, 0, 1, true, true, "2")
        KTILE(T + 1, 1, 0, true, true, "2")
    }
    // epilogue: T=14 (no T+2 stages; vmcnt(0) to cover Bh1(15)), T=15 (drain).
    KTILE(14, 0, 1, false, true, "0")
    KTILE(15, 1, 0, false, false, "0")

#undef KTILE
#undef PHASE_END
#undef STAGE_AH
#undef STAGE_BH
#undef LDA
#undef LDB
}

// ---------------------------------------------------------------------------
// QKV: grid=(64 mt, 12 nt); nt>>2: 0=q 1=k (both elu+1) 2=v. All bf16 out.
// ---------------------------------------------------------------------------
__global__ __launch_bounds__(512) void gemm_qkv_256(
    const __bf16* __restrict__ xb,
    const __bf16* __restrict__ wqt, const __bf16* __restrict__ wkt,
    const __bf16* __restrict__ wvt,
    const float* __restrict__ bq, const float* __restrict__ bk,
    const float* __restrict__ bv,
    __bf16* __restrict__ qfb, __bf16* __restrict__ kfb, __bf16* __restrict__ vb)
{
    f32x4 acc[8][4];
#pragma unroll
    for (int i = 0; i < 8; ++i)
#pragma unroll
        for (int j = 0; j < 4; ++j) acc[i][j] = (f32x4){0.f, 0.f, 0.f, 0.f};

    const int mt = blockIdx.x;
    const int nt = blockIdx.y;
    const int which = nt >> 2;
    const int nbase = (nt & 3) * 256;
    const int mbase = mt * 256;

    const __bf16* BT  = (which == 0) ? wqt : (which == 1) ? wkt : wvt;
    const float* bias = (which == 0) ? bq : (which == 1) ? bk : bv;
    __bf16* outp      = (which == 0) ? qfb : (which == 1) ? kfb : vb;
    const bool feat   = (which < 2);

    mfma256_core(xb, BT, mbase, nbase, acc);

    const int t = threadIdx.x, lane = t & 63, wid = t >> 6;
    const int wm = wid >> 2, wn = wid & 3;
    const int fr = lane & 15, fq = lane >> 4;

#pragma unroll
    for (int ri = 0; ri < 8; ++ri)
#pragma unroll
        for (int cj = 0; cj < 4; ++cj) {
            const int col = nbase + wn * 64 + cj * 16 + fr;
            const float bval = bias[col];
#pragma unroll
            for (int r = 0; r < 4; ++r) {
                const int row = mbase + wm * 128 + ri * 16 + fq * 4 + r;
                float vv = acc[ri][cj][r] + bval;
                if (feat) vv = (vv > 0.f) ? (vv + 1.f) : __expf(vv);
                outp[(size_t)row * 1024 + col] = (__bf16)vv;
            }
        }
}

// ---------------------------------------------------------------------------
// out = y @ WoT + bo (fp32). grid=(64 mt, 4 nt)
// ---------------------------------------------------------------------------
__global__ __launch_bounds__(512) void gemm_out_256(
    const __bf16* __restrict__ yb, const __bf16* __restrict__ wot,
    const float* __restrict__ bo, float* __restrict__ out)
{
    f32x4 acc[8][4];
#pragma unroll
    for (int i = 0; i < 8; ++i)
#pragma unroll
        for (int j = 0; j < 4; ++j) acc[i][j] = (f32x4){0.f, 0.f, 0.f, 0.f};

    const int mbase = blockIdx.x * 256;
    const int nbase = blockIdx.y * 256;

    mfma256_core(yb, wot, mbase, nbase, acc);

    const int t = threadIdx.x, lane = t & 63, wid = t >> 6;
    const int wm = wid >> 2, wn = wid & 3;
    const int fr = lane & 15, fq = lane >> 4;

#pragma unroll
    for (int ri = 0; ri < 8; ++ri)
#pragma unroll
        for (int cj = 0; cj < 4; ++cj) {
            const int col = nbase + wn * 64 + cj * 16 + fr;
            const float bval = bo[col];
#pragma unroll
            for (int r = 0; r < 4; ++r) {
                const int row = mbase + wm * 128 + ri * 16 + fq * 4 + r;
                out[(size_t)row * 1024 + col] = acc[ri][cj][r] + bval;
            }
        }
}

// ---------------------------------------------------------------------------
// kv partials: kvp[bh][chunk][m][d] = sum_{s in chunk} v[s][m]*kf[s][d]
// ksum partials via ones-A MFMA.  grid=(64 bh, 16 chunks of 256 s).
// ---------------------------------------------------------------------------
__global__ __launch_bounds__(256) void kv_ksum_mfma(
    const __bf16* __restrict__ kfb, const __bf16* __restrict__ vb,
    float* __restrict__ kvp, float* __restrict__ ksp)
{
    __shared__ __bf16 kfs[64 * 66];
    __shared__ __bf16 vs[64 * 66];

    const int bh = blockIdx.x;
    const int n = bh >> 4, h = bh & 15;
    const int chunk = blockIdx.y;
    const int t = threadIdx.x, lane = t & 63, w = t >> 6;
    const int fr = lane & 15, fq = lane >> 4;

    f32x4 acc[4];
#pragma unroll
    for (int j = 0; j < 4; j++) acc[j] = (f32x4){0.f, 0.f, 0.f, 0.f};
    f32x4 accks = (f32x4){0.f, 0.f, 0.f, 0.f};

    bf16x8 ones;
#pragma unroll
    for (int e = 0; e < 8; e++) ones[e] = (__bf16)1.0f;

    const size_t base = ((size_t)n * 4096 + (size_t)chunk * 256) * 1024 + h * 64;

    for (int tile = 0; tile < 4; tile++) {
#pragma unroll
        for (int i = 0; i < 2; i++) {
            int idx = t + i * 256;              // 0..511
            int s = idx >> 3, d0 = (idx & 7) * 8;
            bf16x8 k8 = *(const bf16x8*)(kfb + base + (size_t)(tile * 64 + s) * 1024 + d0);
            bf16x8 v8 = *(const bf16x8*)(vb  + base + (size_t)(tile * 64 + s) * 1024 + d0);
#pragma unroll
            for (int e = 0; e < 4; e++) {
                *(bf16x2*)(kfs + s * 66 + d0 + 2 * e) = (bf16x2){k8[2*e], k8[2*e+1]};
                *(bf16x2*)(vs  + s * 66 + d0 + 2 * e) = (bf16x2){v8[2*e], v8[2*e+1]};
            }
        }
        __syncthreads();

#pragma unroll
        for (int kk = 0; kk < 2; kk++) {
            bf16x8 af, bfr[4];
#pragma unroll
            for (int j = 0; j < 8; j++)
                af[j] = vs[(kk * 32 + fq * 8 + j) * 66 + 16 * w + fr];
#pragma unroll
            for (int j2 = 0; j2 < 4; j2++)
#pragma unroll
                for (int j = 0; j < 8; j++)
                    bfr[j2][j] = kfs[(kk * 32 + fq * 8 + j) * 66 + 16 * j2 + fr];
#pragma unroll
            for (int j2 = 0; j2 < 4; j2++)
                acc[j2] = __builtin_amdgcn_mfma_f32_16x16x32_bf16(
                    af, bfr[j2], acc[j2], 0, 0, 0);
            accks = __builtin_amdgcn_mfma_f32_16x16x32_bf16(
                ones, bfr[w], accks, 0, 0, 0);
        }
        __syncthreads();
    }

    const size_t pbase = ((size_t)bh * 16 + chunk) * 4096;
#pragma unroll
    for (int j2 = 0; j2 < 4; j2++)
#pragma unroll
        for (int r = 0; r < 4; r++) {
            int m = 16 * w + fq * 4 + r;
            int d = 16 * j2 + fr;
            kvp[pbase + m * 64 + d] = acc[j2][r];
        }
    if (fq == 0)
        ksp[((size_t)bh * 16 + chunk) * 64 + 16 * w + fr] = accks[0];
}

// ---------------------------------------------------------------------------
// reduce partials -> kvb bf16 [bh][m][d], ksumb bf16 [bh][d]
// ---------------------------------------------------------------------------
__global__ __launch_bounds__(256) void reduce_kv(
    const float* __restrict__ kvp, const float* __restrict__ ksp,
    __bf16* __restrict__ kvb, __bf16* __restrict__ ksumb)
{
    const int b = blockIdx.x;
    if (b < 1024) {
        int i = b * 256 + threadIdx.x;          // 0..262143
        int bh = i >> 12, md = i & 4095;
        float s = 0.f;
#pragma unroll
        for (int c = 0; c < 16; c++) s += kvp[((size_t)bh * 16 + c) * 4096 + md];
        kvb[i] = (__bf16)s;
    } else {
        int j = (b - 1024) * 256 + threadIdx.x; // 0..4095
        int bh = j >> 6, d = j & 63;
        float s = 0.f;
#pragma unroll
        for (int c = 0; c < 16; c++) s += ksp[((size_t)bh * 16 + c) * 64 + d];
        ksumb[j] = (__bf16)s;
    }
}

// ---------------------------------------------------------------------------
// y[g,h,m] = z * sum_d qf[g,h,d]*kv[bh,m,d], z = 1/(qf.ksum+eps)
// grid=(128 gtiles of 128, 16 h)
// ---------------------------------------------------------------------------
__global__ __launch_bounds__(256) void y_mfma(
    const __bf16* __restrict__ qfb, const __bf16* __restrict__ kvb,
    const __bf16* __restrict__ ksumb, __bf16* __restrict__ yb)
{
    __shared__ __bf16 qs[128 * 72];
    __shared__ __bf16 kvs[64 * 72];

    const int gbase = blockIdx.x * 128;
    const int h = blockIdx.y;
    const int bh = (gbase >> 12) * 16 + h;
    const int t = threadIdx.x, lane = t & 63, w = t >> 6;
    const int fr = lane & 15, fq = lane >> 4;

#pragma unroll
    for (int i = 0; i < 4; i++) {
        int idx = t + i * 256;                  // 0..1023
        int l = idx >> 3, d0 = (idx & 7) * 8;
        *(bf16x8*)(qs + l * 72 + d0) =
            *(const bf16x8*)(qfb + (size_t)(gbase + l) * 1024 + h * 64 + d0);
    }
#pragma unroll
    for (int i = 0; i < 2; i++) {
        int idx = t + i * 256;                  // 0..511
        int m = idx >> 3, d0 = (idx & 7) * 8;
        *(bf16x8*)(kvs + m * 72 + d0) =
            *(const bf16x8*)(kvb + (size_t)bh * 4096 + m * 64 + d0);
    }
    bf16x8 ksb[2];
#pragma unroll
    for (int kk = 0; kk < 2; kk++)
        ksb[kk] = *(const bf16x8*)(ksumb + bh * 64 + kk * 32 + fq * 8);
    __syncthreads();

    f32x4 acc[2][4], accz[2];
#pragma unroll
    for (int i = 0; i < 2; i++) {
        accz[i] = (f32x4){0.f, 0.f, 0.f, 0.f};
#pragma unroll
        for (int j = 0; j < 4; j++) acc[i][j] = (f32x4){0.f, 0.f, 0.f, 0.f};
    }

#pragma unroll
    for (int kk = 0; kk < 2; kk++) {
        bf16x8 af[2], bfr[4];
#pragma unroll
        for (int i = 0; i < 2; i++)
            af[i] = *(const bf16x8*)(qs + (32 * w + 16 * i + fr) * 72 + kk * 32 + fq * 8);
#pragma unroll
        for (int j = 0; j < 4; j++)
            bfr[j] = *(const bf16x8*)(kvs + (16 * j + fr) * 72 + kk * 32 + fq * 8);
#pragma unroll
        for (int i = 0; i < 2; i++) {
#pragma unroll
            for (int j = 0; j < 4; j++)
                acc[i][j] = __builtin_amdgcn_mfma_f32_16x16x32_bf16(
                    af[i], bfr[j], acc[i][j], 0, 0, 0);
            accz[i] = __builtin_amdgcn_mfma_f32_16x16x32_bf16(
                af[i], ksb[kk], accz[i], 0, 0, 0);
        }
    }

#pragma unroll
    for (int i = 0; i < 2; i++)
#pragma unroll
        for (int r = 0; r < 4; r++) {
            const float z = 1.0f / (accz[i][r] + 1e-6f);
            const int g = gbase + 32 * w + 16 * i + fq * 4 + r;
#pragma unroll
            for (int j = 0; j < 4; j++)
                yb[(size_t)g * 1024 + h * 64 + 16 * j + fr] =
                    (__bf16)(acc[i][j][r] * z);
        }
}

// ---------------------------------------------------------------------------
__global__ __launch_bounds__(256) void cast_x(const float* __restrict__ x,
                                              __bf16* __restrict__ xb)
{
    const size_t i = ((size_t)blockIdx.x * 256 + threadIdx.x) * 8;
    float4 a = *(const float4*)(x + i);
    float4 b = *(const float4*)(x + i + 4);
    bf16x8 o;
    o[0] = (__bf16)a.x; o[1] = (__bf16)a.y; o[2] = (__bf16)a.z; o[3] = (__bf16)a.w;
    o[4] = (__bf16)b.x; o[5] = (__bf16)b.y; o[6] = (__bf16)b.z; o[7] = (__bf16)b.w;
    *(bf16x8*)(xb + i) = o;
}

__global__ __launch_bounds__(256) void transpose_w(
    const float* __restrict__ w0, const float* __restrict__ w1,
    const float* __restrict__ w2, const float* __restrict__ w3,
    __bf16* __restrict__ o0, __bf16* __restrict__ o1,
    __bf16* __restrict__ o2, __bf16* __restrict__ o3)
{
    __shared__ float ld[32][33];
    const int wsel = blockIdx.z;
    const float* src = (wsel == 0) ? w0 : (wsel == 1) ? w1 : (wsel == 2) ? w2 : w3;
    __bf16* dst      = (wsel == 0) ? o0 : (wsel == 1) ? o1 : (wsel == 2) ? o2 : o3;

    const int kbase = blockIdx.x * 32;
    const int nbase = blockIdx.y * 32;
    const int t = threadIdx.x;
    const int r = t >> 3, c4 = (t & 7) * 4;

    float4 a = *(const float4*)(src + (size_t)(kbase + r) * 1024 + nbase + c4);
    ld[r][c4 + 0] = a.x; ld[r][c4 + 1] = a.y; ld[r][c4 + 2] = a.z; ld[r][c4 + 3] = a.w;
    __syncthreads();

    bf16x4 o;
    o[0] = (__bf16)ld[c4 + 0][r];
    o[1] = (__bf16)ld[c4 + 1][r];
    o[2] = (__bf16)ld[c4 + 2][r];
    o[3] = (__bf16)ld[c4 + 3][r];
    *(bf16x4*)(dst + (size_t)(nbase + r) * 1024 + kbase + c4) = o;
}

extern "C" void kernel_launch(void* const* d_in, const int* in_sizes, int n_in,
                              void* d_out, int out_size, void* d_ws, size_t ws_size,
                              hipStream_t stream)
{
    const float* x  = (const float*)d_in[0];
    const float* Wq = (const float*)d_in[1];
    const float* bq = (const float*)d_in[2];
    const float* Wk = (const float*)d_in[3];
    const float* bk = (const float*)d_in[4];
    const float* Wv = (const float*)d_in[5];
    const float* bv = (const float*)d_in[6];
    const float* Wo = (const float*)d_in[7];
    const float* bo = (const float*)d_in[8];
    float* out = (float*)d_out;

    __bf16* xb    = (__bf16*)d_ws;                   // 16777216
    __bf16* wqt   = xb + (size_t)16777216;           // 1048576 each
    __bf16* wkt   = wqt + 1048576;
    __bf16* wvt   = wkt + 1048576;
    __bf16* wot   = wvt + 1048576;
    __bf16* qfb   = wot + 1048576;                   // 16777216
    __bf16* kfb   = qfb + (size_t)16777216;          // 16777216 (reused as yb)
    __bf16* vb    = kfb + (size_t)16777216;          // 16777216
    float*  kvp   = (float*)(vb + (size_t)16777216); // 4194304 fp32 (16 MB)
    float*  ksp   = kvp + 4194304;                   // 65536 fp32
    __bf16* kvb   = (__bf16*)(ksp + 65536);          // 262144
    __bf16* ksumb = kvb + 262144;                    // 4096

    const int LDS_BYTES = 131072;
    (void)hipFuncSetAttribute((const void*)gemm_qkv_256,
                              hipFuncAttributeMaxDynamicSharedMemorySize, LDS_BYTES);
    (void)hipFuncSetAttribute((const void*)gemm_out_256,
                              hipFuncAttributeMaxDynamicSharedMemorySize, LDS_BYTES);

    cast_x<<<dim3(8192), dim3(256), 0, stream>>>(x, xb);
    transpose_w<<<dim3(32, 32, 4), dim3(256), 0, stream>>>(
        Wq, Wk, Wv, Wo, wqt, wkt, wvt, wot);

    gemm_qkv_256<<<dim3(64, 12), dim3(512), LDS_BYTES, stream>>>(
        xb, wqt, wkt, wvt, bq, bk, bv, qfb, kfb, vb);
    kv_ksum_mfma<<<dim3(64, 16), dim3(256), 0, stream>>>(kfb, vb, kvp, ksp);
    reduce_kv<<<dim3(1040), dim3(256), 0, stream>>>(kvp, ksp, kvb, ksumb);
    y_mfma<<<dim3(128, 16), dim3(256), 0, stream>>>(qfb, kvb, ksumb, kfb);
    gemm_out_256<<<dim3(64, 4), dim3(512), LDS_BYTES, stream>>>(kfb, wot, bo, out);
}

// Round 5
// 453.240 us; speedup vs baseline: 1.1604x; 1.1604x over previous
//
#include <hip/hip_runtime.h>
#include <cstddef>
#include <cstdint>

// LinearAttention B=4,S=4096,D=1024,H=16,Hd=64.  M=16384.
// Round 7: zero-VALU addressing for the 256x256 core.
//  - LDS layout [A:buf0|buf1][B:buf0|buf1] -> every ds_read = one of 4 static
//    per-lane base pointers + compile-time immediate (buf*32768+ri*2048<64K).
//  - 8 static global stage pointers; stage addr = base + tile*64.
//  - R3 phase schedule (proven), rolled main loop (literal buffers), explicit
//    epilogue tiles 12..15 with the T=15 Bh1 race fixed (vmcnt(0) @ p2(14)).
//  - y_mfma: R2 direct-store form (R3 staging cost ~9us).
//  - kv_ksum / reduce / cast / transpose unchanged.

typedef __attribute__((ext_vector_type(8))) __bf16 bf16x8;
typedef __attribute__((ext_vector_type(4))) __bf16 bf16x4;
typedef __attribute__((ext_vector_type(2))) __bf16 bf16x2;
typedef __attribute__((ext_vector_type(4))) float f32x4;

__device__ __forceinline__ void async_cp16(const void* g, void* s) {
    __builtin_amdgcn_global_load_lds(
        (__attribute__((address_space(1))) void*)g,
        (__attribute__((address_space(3))) void*)s, 16, 0, 0);
}

// ---------------------------------------------------------------------------
// 256x256 C-tile of A[.,1024]_bf16 x BT[1024,1024]_bf16^T, K=1024, BK=64.
// 512 threads = 8 waves (2M x 4N), per-wave 128x64 output.
// LDS bytes: A-half(16K): buf*32768 + hh*16384 + c*1024 + lane*16; B at +65536.
// Swizzle: row r slot s holds k-chunk s^(r&7) (pre-swizzled global source,
// linear LDS dest); reads XOR the chunk with (fr&7) -> per-lane-constant,
// baked into the 4 static base pointers (A/B x ks0/ks1).
//
// Per K-tile T (BUF literal), one barrier per phase (R3 schedule):
//   p0: reads aR1(T),bC1(T)[BUF]; stage Bh1(T+1)->BUF^1 | MFMA r0c0
//   p1: vmcnt(4);                 stage Ah0(T+2)->BUF    | MFMA r0c1
//   p2: vmcnt(P2W); reads aR0(T+1)[BUF^1]; stage Ah1(T+2)| MFMA r1c0
//   p3: reads bC0(T+1)[BUF^1];    stage Bh0(T+2)->BUF    | MFMA r1c1
// Phase end: lgkmcnt(0); s_barrier.  Covering waits (FIFO-verified):
//   steady: vmcnt(4)@p1 retires Ah0/Ah1(T+1); vmcnt(2)@p2 retires Bh0/Bh1(T+1)
//   T=14: vmcnt(0)@p2 (covers Bh1(15) for p0(15) read - fixes R3 latent race)
// ---------------------------------------------------------------------------

#define QUAD(ARR, BRR, RO, CO)                                                 \
    _Pragma("unroll")                                                          \
    for (int _qi = 0; _qi < 4; ++_qi)                                          \
        _Pragma("unroll")                                                      \
        for (int _qj = 0; _qj < 2; ++_qj)                                      \
            _Pragma("unroll")                                                  \
            for (int _qk = 0; _qk < 2; ++_qk)                                  \
                acc[(RO) + _qi][(CO) + _qj] =                                  \
                    __builtin_amdgcn_mfma_f32_16x16x32_bf16(                   \
                        ARR[_qi][_qk], BRR[_qj][_qk],                          \
                        acc[(RO) + _qi][(CO) + _qj], 0, 0, 0);

__device__ __forceinline__ void mfma256_core(const __bf16* __restrict__ A,
                                             const __bf16* __restrict__ BT,
                                             int mbase, int nbase,
                                             f32x4 acc[8][4])
{
    extern __shared__ char ldsb[];
    const int t    = threadIdx.x;
    const int lane = t & 63;
    const int wid  = t >> 6;                     // 0..7
    const int wm   = wid >> 2;                   // 0..1
    const int wn   = wid & 3;                    // 0..3
    const int fr   = lane & 15;
    const int fq   = lane >> 4;
    const int srow  = lane >> 3;                 // 0..7
    const int sslot = ((lane & 7) ^ srow) << 3;  // pre-swizzled k-chunk (elems)

    // 4 static LDS read base pointers (per-lane; all loop offsets are imms).
    const char* pA0 = ldsb + wm * 16384 + fr * 128 + ((fq ^ (fr & 7)) * 16);
    const char* pA1 = ldsb + wm * 16384 + fr * 128 + (((4 + fq) ^ (fr & 7)) * 16);
    const char* pB0 = ldsb + 65536 + (wn >> 1) * 16384 + ((wn & 1) * 64 + fr) * 128
                           + ((fq ^ (fr & 7)) * 16);
    const char* pB1 = ldsb + 65536 + (wn >> 1) * 16384 + ((wn & 1) * 64 + fr) * 128
                           + (((4 + fq) ^ (fr & 7)) * 16);

    // 8 static global stage base pointers (tile advance = +tile*64 elems).
    const __bf16* gA00 = A  + (size_t)(mbase + 0   + (2 * wid + 0) * 8 + srow) * 1024 + sslot;
    const __bf16* gA01 = A  + (size_t)(mbase + 0   + (2 * wid + 1) * 8 + srow) * 1024 + sslot;
    const __bf16* gA10 = A  + (size_t)(mbase + 128 + (2 * wid + 0) * 8 + srow) * 1024 + sslot;
    const __bf16* gA11 = A  + (size_t)(mbase + 128 + (2 * wid + 1) * 8 + srow) * 1024 + sslot;
    const __bf16* gB00 = BT + (size_t)(nbase + 0   + (2 * wid + 0) * 8 + srow) * 1024 + sslot;
    const __bf16* gB01 = BT + (size_t)(nbase + 0   + (2 * wid + 1) * 8 + srow) * 1024 + sslot;
    const __bf16* gB10 = BT + (size_t)(nbase + 128 + (2 * wid + 0) * 8 + srow) * 1024 + sslot;
    const __bf16* gB11 = BT + (size_t)(nbase + 128 + (2 * wid + 1) * 8 + srow) * 1024 + sslot;

#define LDA(ri, ks, BUF)                                                       \
    (*(const bf16x8*)(((ks) ? pA1 : pA0) + (BUF) * 32768 + (ri) * 2048))
#define LDB(cj, ks, BUF)                                                       \
    (*(const bf16x8*)(((ks) ? pB1 : pB0) + (BUF) * 32768 + (cj) * 2048))

#define STAGE_AH(tile, hh, BUF)                                                \
    { async_cp16((hh ? gA10 : gA00) + (size_t)(tile) * 64,                     \
                 ldsb + (BUF) * 32768 + (hh) * 16384 + (2 * wid + 0) * 1024);  \
      async_cp16((hh ? gA11 : gA01) + (size_t)(tile) * 64,                     \
                 ldsb + (BUF) * 32768 + (hh) * 16384 + (2 * wid + 1) * 1024); }
#define STAGE_BH(tile, hh, BUF)                                                \
    { async_cp16((hh ? gB10 : gB00) + (size_t)(tile) * 64,                     \
                 ldsb + 65536 + (BUF) * 32768 + (hh) * 16384 + (2 * wid + 0) * 1024); \
      async_cp16((hh ? gB11 : gB01) + (size_t)(tile) * 64,                     \
                 ldsb + 65536 + (BUF) * 32768 + (hh) * 16384 + (2 * wid + 1) * 1024); }

#define PHASE_END                                                              \
    asm volatile("s_waitcnt lgkmcnt(0)" ::: "memory");                         \
    __builtin_amdgcn_s_barrier();

#define KTILE(T, BUF, S2, NX, P2W)                                             \
    {                                                                          \
        /* ---- p0 ---- */                                                     \
        _Pragma("unroll") for (int _i = 0; _i < 4; ++_i) {                     \
            aR1[_i][0] = LDA(4 + _i, 0, BUF);                                  \
            aR1[_i][1] = LDA(4 + _i, 1, BUF);                                  \
        }                                                                      \
        _Pragma("unroll") for (int _j = 0; _j < 2; ++_j) {                     \
            bC1[_j][0] = LDB(2 + _j, 0, BUF);                                  \
            bC1[_j][1] = LDB(2 + _j, 1, BUF);                                  \
        }                                                                      \
        if (NX) STAGE_BH((T) + 1, 1, (BUF) ^ 1)                                \
        __builtin_amdgcn_sched_barrier(0);                                     \
        __builtin_amdgcn_s_setprio(1);                                         \
        QUAD(aR0, bC0, 0, 0)                                                   \
        __builtin_amdgcn_s_setprio(0);                                         \
        PHASE_END                                                              \
        /* ---- p1 ---- */                                                     \
        if (NX) asm volatile("s_waitcnt vmcnt(4)" ::: "memory");               \
        if (S2) STAGE_AH((T) + 2, 0, BUF)                                      \
        __builtin_amdgcn_sched_barrier(0);                                     \
        __builtin_amdgcn_s_setprio(1);                                         \
        QUAD(aR0, bC1, 0, 2)                                                   \
        __builtin_amdgcn_s_setprio(0);                                         \
        PHASE_END                                                              \
        /* ---- p2 ---- */                                                     \
        if (NX) asm volatile("s_waitcnt vmcnt(" P2W ")" ::: "memory");         \
        if (NX) {                                                              \
            _Pragma("unroll") for (int _i = 0; _i < 4; ++_i) {                 \
                aR0[_i][0] = LDA(_i, 0, (BUF) ^ 1);                            \
                aR0[_i][1] = LDA(_i, 1, (BUF) ^ 1);                            \
            }                                                                  \
        }                                                                      \
        if (S2) STAGE_AH((T) + 2, 1, BUF)                                      \
        __builtin_amdgcn_sched_barrier(0);                                     \
        __builtin_amdgcn_s_setprio(1);                                         \
        QUAD(aR1, bC0, 4, 0)                                                   \
        __builtin_amdgcn_s_setprio(0);                                         \
        PHASE_END                                                              \
        /* ---- p3 ---- */                                                     \
        if (NX) {                                                              \
            _Pragma("unroll") for (int _j = 0; _j < 2; ++_j) {                 \
                bC0[_j][0] = LDB(_j, 0, (BUF) ^ 1);                            \
                bC0[_j][1] = LDB(_j, 1, (BUF) ^ 1);                            \
            }                                                                  \
        }                                                                      \
        if (S2) STAGE_BH((T) + 2, 0, BUF)                                      \
        __builtin_amdgcn_sched_barrier(0);                                     \
        __builtin_amdgcn_s_setprio(1);                                         \
        QUAD(aR1, bC1, 4, 2)                                                   \
        __builtin_amdgcn_s_setprio(0);                                         \
        PHASE_END                                                              \
    }

    bf16x8 aR0[4][2], aR1[4][2], bC0[2][2], bC1[2][2];

    // prologue: tile0 fully + tile1 A-halves + Bh0(1); Bh1(1) staged at p0(0).
    STAGE_AH(0, 0, 0) STAGE_AH(0, 1, 0) STAGE_BH(0, 0, 0) STAGE_BH(0, 1, 0)
    STAGE_AH(1, 0, 1) STAGE_AH(1, 1, 1) STAGE_BH(1, 0, 1)
    asm volatile("s_waitcnt vmcnt(6)" ::: "memory");   // tile0's 8 retired
    __builtin_amdgcn_s_barrier();

#pragma unroll
    for (int i = 0; i < 4; ++i) {
        aR0[i][0] = LDA(i, 0, 0);
        aR0[i][1] = LDA(i, 1, 0);
    }
#pragma unroll
    for (int j = 0; j < 2; ++j) {
        bC0[j][0] = LDB(j, 0, 0);
        bC0[j][1] = LDB(j, 1, 0);
    }

    // main loop: tiles 0..11 (all-full, literal buffers, no branches).
    for (int T = 0; T < 12; T += 2) {
        KTILE(T, 0, true, true, "2")
        KTILE(T + 1, 1, true, true, "2")
    }
    // epilogue: literal tiles (stage addrs fold to immediates).
    KTILE(12, 0, true, true, "2")
    KTILE(13, 1, true, true, "2")
    KTILE(14, 0, false, true, "0")     // vmcnt(0)@p2 covers Bh1(15)
    KTILE(15, 1, false, false, "0")

#undef KTILE
#undef PHASE_END
#undef STAGE_AH
#undef STAGE_BH
#undef LDA
#undef LDB
}

// ---------------------------------------------------------------------------
// QKV: grid=(64 mt, 12 nt); nt>>2: 0=q 1=k (both elu+1) 2=v. All bf16 out.
// ---------------------------------------------------------------------------
__global__ __launch_bounds__(512, 2) void gemm_qkv_256(
    const __bf16* __restrict__ xb,
    const __bf16* __restrict__ wqt, const __bf16* __restrict__ wkt,
    const __bf16* __restrict__ wvt,
    const float* __restrict__ bq, const float* __restrict__ bk,
    const float* __restrict__ bv,
    __bf16* __restrict__ qfb, __bf16* __restrict__ kfb, __bf16* __restrict__ vb)
{
    f32x4 acc[8][4];
#pragma unroll
    for (int i = 0; i < 8; ++i)
#pragma unroll
        for (int j = 0; j < 4; ++j) acc[i][j] = (f32x4){0.f, 0.f, 0.f, 0.f};

    const int mt = blockIdx.x;
    const int nt = blockIdx.y;
    const int which = nt >> 2;
    const int nbase = (nt & 3) * 256;
    const int mbase = mt * 256;

    const __bf16* BT  = (which == 0) ? wqt : (which == 1) ? wkt : wvt;
    const float* bias = (which == 0) ? bq : (which == 1) ? bk : bv;
    __bf16* outp      = (which == 0) ? qfb : (which == 1) ? kfb : vb;
    const bool feat   = (which < 2);

    mfma256_core(xb, BT, mbase, nbase, acc);

    const int t = threadIdx.x, lane = t & 63, wid = t >> 6;
    const int wm = wid >> 2, wn = wid & 3;
    const int fr = lane & 15, fq = lane >> 4;

#pragma unroll
    for (int ri = 0; ri < 8; ++ri)
#pragma unroll
        for (int cj = 0; cj < 4; ++cj) {
            const int col = nbase + wn * 64 + cj * 16 + fr;
            const float bval = bias[col];
#pragma unroll
            for (int r = 0; r < 4; ++r) {
                const int row = mbase + wm * 128 + ri * 16 + fq * 4 + r;
                float vv = acc[ri][cj][r] + bval;
                if (feat) vv = (vv > 0.f) ? (vv + 1.f) : __expf(vv);
                outp[(size_t)row * 1024 + col] = (__bf16)vv;
            }
        }
}

// ---------------------------------------------------------------------------
// out = y @ WoT + bo (fp32). grid=(64 mt, 4 nt)
// ---------------------------------------------------------------------------
__global__ __launch_bounds__(512, 2) void gemm_out_256(
    const __bf16* __restrict__ yb, const __bf16* __restrict__ wot,
    const float* __restrict__ bo, float* __restrict__ out)
{
    f32x4 acc[8][4];
#pragma unroll
    for (int i = 0; i < 8; ++i)
#pragma unroll
        for (int j = 0; j < 4; ++j) acc[i][j] = (f32x4){0.f, 0.f, 0.f, 0.f};

    const int mbase = blockIdx.x * 256;
    const int nbase = blockIdx.y * 256;

    mfma256_core(yb, wot, mbase, nbase, acc);

    const int t = threadIdx.x, lane = t & 63, wid = t >> 6;
    const int wm = wid >> 2, wn = wid & 3;
    const int fr = lane & 15, fq = lane >> 4;

#pragma unroll
    for (int ri = 0; ri < 8; ++ri)
#pragma unroll
        for (int cj = 0; cj < 4; ++cj) {
            const int col = nbase + wn * 64 + cj * 16 + fr;
            const float bval = bo[col];
#pragma unroll
            for (int r = 0; r < 4; ++r) {
                const int row = mbase + wm * 128 + ri * 16 + fq * 4 + r;
                out[(size_t)row * 1024 + col] = acc[ri][cj][r] + bval;
            }
        }
}

// ---------------------------------------------------------------------------
// kv partials: kvp[bh][chunk][m][d] = sum_{s in chunk} v[s][m]*kf[s][d]
// ksum partials via ones-A MFMA.  grid=(64 bh, 16 chunks of 256 s).
// ---------------------------------------------------------------------------
__global__ __launch_bounds__(256) void kv_ksum_mfma(
    const __bf16* __restrict__ kfb, const __bf16* __restrict__ vb,
    float* __restrict__ kvp, float* __restrict__ ksp)
{
    __shared__ __bf16 kfs[64 * 66];
    __shared__ __bf16 vs[64 * 66];

    const int bh = blockIdx.x;
    const int n = bh >> 4, h = bh & 15;
    const int chunk = blockIdx.y;
    const int t = threadIdx.x, lane = t & 63, w = t >> 6;
    const int fr = lane & 15, fq = lane >> 4;

    f32x4 acc[4];
#pragma unroll
    for (int j = 0; j < 4; j++) acc[j] = (f32x4){0.f, 0.f, 0.f, 0.f};
    f32x4 accks = (f32x4){0.f, 0.f, 0.f, 0.f};

    bf16x8 ones;
#pragma unroll
    for (int e = 0; e < 8; e++) ones[e] = (__bf16)1.0f;

    const size_t base = ((size_t)n * 4096 + (size_t)chunk * 256) * 1024 + h * 64;

    for (int tile = 0; tile < 4; tile++) {
#pragma unroll
        for (int i = 0; i < 2; i++) {
            int idx = t + i * 256;              // 0..511
            int s = idx >> 3, d0 = (idx & 7) * 8;
            bf16x8 k8 = *(const bf16x8*)(kfb + base + (size_t)(tile * 64 + s) * 1024 + d0);
            bf16x8 v8 = *(const bf16x8*)(vb  + base + (size_t)(tile * 64 + s) * 1024 + d0);
#pragma unroll
            for (int e = 0; e < 4; e++) {
                *(bf16x2*)(kfs + s * 66 + d0 + 2 * e) = (bf16x2){k8[2*e], k8[2*e+1]};
                *(bf16x2*)(vs  + s * 66 + d0 + 2 * e) = (bf16x2){v8[2*e], v8[2*e+1]};
            }
        }
        __syncthreads();

#pragma unroll
        for (int kk = 0; kk < 2; kk++) {
            bf16x8 af, bfr[4];
#pragma unroll
            for (int j = 0; j < 8; j++)
                af[j] = vs[(kk * 32 + fq * 8 + j) * 66 + 16 * w + fr];
#pragma unroll
            for (int j2 = 0; j2 < 4; j2++)
#pragma unroll
                for (int j = 0; j < 8; j++)
                    bfr[j2][j] = kfs[(kk * 32 + fq * 8 + j) * 66 + 16 * j2 + fr];
#pragma unroll
            for (int j2 = 0; j2 < 4; j2++)
                acc[j2] = __builtin_amdgcn_mfma_f32_16x16x32_bf16(
                    af, bfr[j2], acc[j2], 0, 0, 0);
            accks = __builtin_amdgcn_mfma_f32_16x16x32_bf16(
                ones, bfr[w], accks, 0, 0, 0);
        }
        __syncthreads();
    }

    const size_t pbase = ((size_t)bh * 16 + chunk) * 4096;
#pragma unroll
    for (int j2 = 0; j2 < 4; j2++)
#pragma unroll
        for (int r = 0; r < 4; r++) {
            int m = 16 * w + fq * 4 + r;
            int d = 16 * j2 + fr;
            kvp[pbase + m * 64 + d] = acc[j2][r];
        }
    if (fq == 0)
        ksp[((size_t)bh * 16 + chunk) * 64 + 16 * w + fr] = accks[0];
}

// ---------------------------------------------------------------------------
// reduce partials -> kvb bf16 [bh][m][d], ksumb bf16 [bh][d]
// ---------------------------------------------------------------------------
__global__ __launch_bounds__(256) void reduce_kv(
    const float* __restrict__ kvp, const float* __restrict__ ksp,
    __bf16* __restrict__ kvb, __bf16* __restrict__ ksumb)
{
    const int b = blockIdx.x;
    if (b < 1024) {
        int i = b * 256 + threadIdx.x;          // 0..262143
        int bh = i >> 12, md = i & 4095;
        float s = 0.f;
#pragma unroll
        for (int c = 0; c < 16; c++) s += kvp[((size_t)bh * 16 + c) * 4096 + md];
        kvb[i] = (__bf16)s;
    } else {
        int j = (b - 1024) * 256 + threadIdx.x; // 0..4095
        int bh = j >> 6, d = j & 63;
        float s = 0.f;
#pragma unroll
        for (int c = 0; c < 16; c++) s += ksp[((size_t)bh * 16 + c) * 64 + d];
        ksumb[j] = (__bf16)s;
    }
}

// ---------------------------------------------------------------------------
// y[g,h,m] = z * sum_d qf[g,h,d]*kv[bh,m,d], z = 1/(qf.ksum+eps)
// grid=(128 gtiles of 128, 16 h)
// ---------------------------------------------------------------------------
__global__ __launch_bounds__(256) void y_mfma(
    const __bf16* __restrict__ qfb, const __bf16* __restrict__ kvb,
    const __bf16* __restrict__ ksumb, __bf16* __restrict__ yb)
{
    __shared__ __bf16 qs[128 * 72];
    __shared__ __bf16 kvs[64 * 72];

    const int gbase = blockIdx.x * 128;
    const int h = blockIdx.y;
    const int bh = (gbase >> 12) * 16 + h;
    const int t = threadIdx.x, lane = t & 63, w = t >> 6;
    const int fr = lane & 15, fq = lane >> 4;

#pragma unroll
    for (int i = 0; i < 4; i++) {
        int idx = t + i * 256;                  // 0..1023
        int l = idx >> 3, d0 = (idx & 7) * 8;
        *(bf16x8*)(qs + l * 72 + d0) =
            *(const bf16x8*)(qfb + (size_t)(gbase + l) * 1024 + h * 64 + d0);
    }
#pragma unroll
    for (int i = 0; i < 2; i++) {
        int idx = t + i * 256;                  // 0..511
        int m = idx >> 3, d0 = (idx & 7) * 8;
        *(bf16x8*)(kvs + m * 72 + d0) =
            *(const bf16x8*)(kvb + (size_t)bh * 4096 + m * 64 + d0);
    }
    bf16x8 ksb[2];
#pragma unroll
    for (int kk = 0; kk < 2; kk++)
        ksb[kk] = *(const bf16x8*)(ksumb + bh * 64 + kk * 32 + fq * 8);
    __syncthreads();

    f32x4 acc[2][4], accz[2];
#pragma unroll
    for (int i = 0; i < 2; i++) {
        accz[i] = (f32x4){0.f, 0.f, 0.f, 0.f};
#pragma unroll
        for (int j = 0; j < 4; j++) acc[i][j] = (f32x4){0.f, 0.f, 0.f, 0.f};
    }

#pragma unroll
    for (int kk = 0; kk < 2; kk++) {
        bf16x8 af[2], bfr[4];
#pragma unroll
        for (int i = 0; i < 2; i++)
            af[i] = *(const bf16x8*)(qs + (32 * w + 16 * i + fr) * 72 + kk * 32 + fq * 8);
#pragma unroll
        for (int j = 0; j < 4; j++)
            bfr[j] = *(const bf16x8*)(kvs + (16 * j + fr) * 72 + kk * 32 + fq * 8);
#pragma unroll
        for (int i = 0; i < 2; i++) {
#pragma unroll
            for (int j = 0; j < 4; j++)
                acc[i][j] = __builtin_amdgcn_mfma_f32_16x16x32_bf16(
                    af[i], bfr[j], acc[i][j], 0, 0, 0);
            accz[i] = __builtin_amdgcn_mfma_f32_16x16x32_bf16(
                af[i], ksb[kk], accz[i], 0, 0, 0);
        }
    }

#pragma unroll
    for (int i = 0; i < 2; i++)
#pragma unroll
        for (int r = 0; r < 4; r++) {
            const float z = 1.0f / (accz[i][r] + 1e-6f);
            const int g = gbase + 32 * w + 16 * i + fq * 4 + r;
#pragma unroll
            for (int j = 0; j < 4; j++)
                yb[(size_t)g * 1024 + h * 64 + 16 * j + fr] =
                    (__bf16)(acc[i][j][r] * z);
        }
}

// ---------------------------------------------------------------------------
__global__ __launch_bounds__(256) void cast_x(const float* __restrict__ x,
                                              __bf16* __restrict__ xb)
{
    const size_t i = ((size_t)blockIdx.x * 256 + threadIdx.x) * 8;
    float4 a = *(const float4*)(x + i);
    float4 b = *(const float4*)(x + i + 4);
    bf16x8 o;
    o[0] = (__bf16)a.x; o[1] = (__bf16)a.y; o[2] = (__bf16)a.z; o[3] = (__bf16)a.w;
    o[4] = (__bf16)b.x; o[5] = (__bf16)b.y; o[6] = (__bf16)b.z; o[7] = (__bf16)b.w;
    *(bf16x8*)(xb + i) = o;
}

__global__ __launch_bounds__(256) void transpose_w(
    const float* __restrict__ w0, const float* __restrict__ w1,
    const float* __restrict__ w2, const float* __restrict__ w3,
    __bf16* __restrict__ o0, __bf16* __restrict__ o1,
    __bf16* __restrict__ o2, __bf16* __restrict__ o3)
{
    __shared__ float ld[32][33];
    const int wsel = blockIdx.z;
    const float* src = (wsel == 0) ? w0 : (wsel == 1) ? w1 : (wsel == 2) ? w2 : w3;
    __bf16* dst      = (wsel == 0) ? o0 : (wsel == 1) ? o1 : (wsel == 2) ? o2 : o3;

    const int kbase = blockIdx.x * 32;
    const int nbase = blockIdx.y * 32;
    const int t = threadIdx.x;
    const int r = t >> 3, c4 = (t & 7) * 4;

    float4 a = *(const float4*)(src + (size_t)(kbase + r) * 1024 + nbase + c4);
    ld[r][c4 + 0] = a.x; ld[r][c4 + 1] = a.y; ld[r][c4 + 2] = a.z; ld[r][c4 + 3] = a.w;
    __syncthreads();

    bf16x4 o;
    o[0] = (__bf16)ld[c4 + 0][r];
    o[1] = (__bf16)ld[c4 + 1][r];
    o[2] = (__bf16)ld[c4 + 2][r];
    o[3] = (__bf16)ld[c4 + 3][r];
    *(bf16x4*)(dst + (size_t)(nbase + r) * 1024 + kbase + c4) = o;
}

extern "C" void kernel_launch(void* const* d_in, const int* in_sizes, int n_in,
                              void* d_out, int out_size, void* d_ws, size_t ws_size,
                              hipStream_t stream)
{
    const float* x  = (const float*)d_in[0];
    const float* Wq = (const float*)d_in[1];
    const float* bq = (const float*)d_in[2];
    const float* Wk = (const float*)d_in[3];
    const float* bk = (const float*)d_in[4];
    const float* Wv = (const float*)d_in[5];
    const float* bv = (const float*)d_in[6];
    const float* Wo = (const float*)d_in[7];
    const float* bo = (const float*)d_in[8];
    float* out = (float*)d_out;

    __bf16* xb    = (__bf16*)d_ws;                   // 16777216
    __bf16* wqt   = xb + (size_t)16777216;           // 1048576 each
    __bf16* wkt   = wqt + 1048576;
    __bf16* wvt   = wkt + 1048576;
    __bf16* wot   = wvt + 1048576;
    __bf16* qfb   = wot + 1048576;                   // 16777216
    __bf16* kfb   = qfb + (size_t)16777216;          // 16777216 (reused as yb)
    __bf16* vb    = kfb + (size_t)16777216;          // 16777216
    float*  kvp   = (float*)(vb + (size_t)16777216); // 4194304 fp32 (16 MB)
    float*  ksp   = kvp + 4194304;                   // 65536 fp32
    __bf16* kvb   = (__bf16*)(ksp + 65536);          // 262144
    __bf16* ksumb = kvb + 262144;                    // 4096

    const int LDS_BYTES = 131072;
    (void)hipFuncSetAttribute((const void*)gemm_qkv_256,
                              hipFuncAttributeMaxDynamicSharedMemorySize, LDS_BYTES);
    (void)hipFuncSetAttribute((const void*)gemm_out_256,
                              hipFuncAttributeMaxDynamicSharedMemorySize, LDS_BYTES);

    cast_x<<<dim3(8192), dim3(256), 0, stream>>>(x, xb);
    transpose_w<<<dim3(32, 32, 4), dim3(256), 0, stream>>>(
        Wq, Wk, Wv, Wo, wqt, wkt, wvt, wot);

    gemm_qkv_256<<<dim3(64, 12), dim3(512), LDS_BYTES, stream>>>(
        xb, wqt, wkt, wvt, bq, bk, bv, qfb, kfb, vb);
    kv_ksum_mfma<<<dim3(64, 16), dim3(256), 0, stream>>>(kfb, vb, kvp, ksp);
    reduce_kv<<<dim3(1040), dim3(256), 0, stream>>>(kvp, ksp, kvb, ksumb);
    y_mfma<<<dim3(128, 16), dim3(256), 0, stream>>>(qfb, kvb, ksumb, kfb);
    gemm_out_256<<<dim3(64, 4), dim3(512), LDS_BYTES, stream>>>(kfb, wot, bo, out);
}

// Round 6
// 326.983 us; speedup vs baseline: 1.6085x; 1.3861x over previous
//
#include <hip/hip_runtime.h>
#include <cstddef>
#include <cstdint>

// LinearAttention B=4,S=4096,D=1024,H=16,Hd=64.  M=16384.
// Round 8 (consolidation): proven components only.
//  - mfma256_core: R3 drain-after schedule (113.5us), main loop T=0..13 +
//    peeled T=14/15 epilogue with vmcnt(0)@p2(14) closing the Bh1(15) race.
//  - y_mfma: R2 direct-store form.
//  - XCD-bijective block swizzle on gemm_qkv_256 (768 blk) / gemm_out_256 (256).
//  - cast_x + transpose_w merged into one prep kernel.

typedef __attribute__((ext_vector_type(8))) __bf16 bf16x8;
typedef __attribute__((ext_vector_type(4))) __bf16 bf16x4;
typedef __attribute__((ext_vector_type(2))) __bf16 bf16x2;
typedef __attribute__((ext_vector_type(4))) float f32x4;

__device__ __forceinline__ void async_cp16(const void* g, void* s) {
    __builtin_amdgcn_global_load_lds(
        (__attribute__((address_space(1))) void*)g,
        (__attribute__((address_space(3))) void*)s, 16, 0, 0);
}

// ---------------------------------------------------------------------------
// 256x256 C-tile of A[.,1024]_bf16 x BT[1024,1024]_bf16^T, K=1024, BK=64.
// 512 threads = 8 waves (2M x 4N), per-wave 128x64 output.
// LDS: 2 buffers x (A 256x64 + B 256x64) bf16 = 128 KiB (dynamic).
// Swizzle: row r slot s holds k-chunk s^(r&7) (pre-swizzled global source,
// linear LDS dest per global_load_lds rules); reads XOR the chunk index.
//
// Per K-tile T (bc=T&1, bn=bc^1), ONE barrier per phase, drain after MFMA:
//   p0: reads aR1(T),bC1(T)[bc];  stage Bh1(T+1)->bn | MFMA r0c0(aR0,bC0)
//   p1: vmcnt(4);                 stage Ah0(T+2)->bc | MFMA r0c1(aR0,bC1)
//   p2: vmcnt(2); reads aR0(T+1)[bn]; stage Ah1(T+2) | MFMA r1c0(aR1,bC0)
//   p3: reads bC0(T+1)[bn];       stage Bh0(T+2)->bc | MFMA r1c1(aR1,bC1)
// Phase end: lgkmcnt(0); s_barrier  (cross-wave write-after-read guard and
// read-drain for next phase's MFMA operands).
// Covering waits (FIFO ledger, 2 loads/half, verified incl. cross-wave):
//   steady (T<=13): before p1 wait queue = {Ah0,Ah1,Bh0,Bh1}(T+1)=8 ->
//     vmcnt(4) retires A(T+1); after p1 stage queue=6 -> vmcnt(2)@p2 retires
//     Bh0(T+1)+Bh1(T+1); each wait is followed by that phase's end barrier
//     before any wave reads the covered region.
//   T=14: no Ah0(16) stage -> vmcnt(2)@p2 would leave Bh1(15) uncovered for
//     p0(15) (latent race in R3) -> use vmcnt(0)@p2(14).  T=15: no waits.
// ---------------------------------------------------------------------------

#define QUAD(ARR, BRR, RO, CO)                                                 \
    _Pragma("unroll")                                                          \
    for (int _qi = 0; _qi < 4; ++_qi)                                          \
        _Pragma("unroll")                                                      \
        for (int _qj = 0; _qj < 2; ++_qj)                                      \
            _Pragma("unroll")                                                  \
            for (int _qk = 0; _qk < 2; ++_qk)                                  \
                acc[(RO) + _qi][(CO) + _qj] =                                  \
                    __builtin_amdgcn_mfma_f32_16x16x32_bf16(                   \
                        ARR[_qi][_qk], BRR[_qj][_qk],                          \
                        acc[(RO) + _qi][(CO) + _qj], 0, 0, 0);

__device__ __forceinline__ void mfma256_core(const __bf16* __restrict__ A,
                                             const __bf16* __restrict__ BT,
                                             int mbase, int nbase,
                                             f32x4 acc[8][4])
{
    extern __shared__ __bf16 lds[];
    const int t    = threadIdx.x;
    const int lane = t & 63;
    const int wid  = t >> 6;                     // 0..7
    const int wm   = wid >> 2;                   // 0..1
    const int wn   = wid & 3;                    // 0..3
    const int fr   = lane & 15;
    const int fq   = lane >> 4;
    const int srow  = lane >> 3;                 // 0..7
    const int sslot = ((lane & 7) ^ srow) << 3;  // pre-swizzled k-chunk (elems)

    const __bf16* aBase = A  + (size_t)mbase * 1024;
    const __bf16* bBase = BT + (size_t)nbase * 1024;

#define STAGE_AH(tile, hh, bb)                                                 \
    { _Pragma("unroll") for (int _i = 0; _i < 2; ++_i) {                       \
          const int _c = 2 * wid + _i;                                         \
          async_cp16(aBase + (size_t)((hh) * 128 + _c * 8 + srow) * 1024       \
                         + (tile) * 64 + sslot,                                \
                     lds + (bb) * 32768 + (hh) * 8192 + _c * 512); } }
#define STAGE_BH(tile, hh, bb)                                                 \
    { _Pragma("unroll") for (int _i = 0; _i < 2; ++_i) {                       \
          const int _c = 2 * wid + _i;                                         \
          async_cp16(bBase + (size_t)((hh) * 128 + _c * 8 + srow) * 1024       \
                         + (tile) * 64 + sslot,                                \
                     lds + (bb) * 32768 + 16384 + (hh) * 8192 + _c * 512); } }
#define LDA(ri, ks, b)                                                         \
    (*(const bf16x8*)(lds + (b) * 32768 + (wm * 128 + (ri) * 16 + fr) * 64     \
                      + (((ks) * 32 + fq * 8) ^ ((fr & 7) << 3))))
#define LDB(cj, ks, b)                                                         \
    (*(const bf16x8*)(lds + (b) * 32768 + 16384                                \
                      + (wn * 64 + (cj) * 16 + fr) * 64                        \
                      + (((ks) * 32 + fq * 8) ^ ((fr & 7) << 3))))

#define PHASE_END                                                              \
    asm volatile("s_waitcnt lgkmcnt(0)" ::: "memory");                         \
    __builtin_amdgcn_s_barrier();

// One K-tile.  BC/BN: buffer indices (runtime in main loop, literal in
// epilogue).  S2: stage tile T+2 exists.  NX: tile T+1 exists.  P2W: vmcnt
// immediate at p2 (string literal).
#define KTILE(T, BC, BN, S2, NX, P2W)                                          \
    {                                                                          \
        /* ---- p0 ---- */                                                     \
        _Pragma("unroll") for (int _i = 0; _i < 4; ++_i) {                     \
            aR1[_i][0] = LDA(4 + _i, 0, BC);                                   \
            aR1[_i][1] = LDA(4 + _i, 1, BC);                                   \
        }                                                                      \
        _Pragma("unroll") for (int _j = 0; _j < 2; ++_j) {                     \
            bC1[_j][0] = LDB(2 + _j, 0, BC);                                   \
            bC1[_j][1] = LDB(2 + _j, 1, BC);                                   \
        }                                                                      \
        if (NX) STAGE_BH((T) + 1, 1, BN)                                       \
        __builtin_amdgcn_sched_barrier(0);                                     \
        __builtin_amdgcn_s_setprio(1);                                         \
        QUAD(aR0, bC0, 0, 0)                                                   \
        __builtin_amdgcn_s_setprio(0);                                         \
        PHASE_END                                                              \
        /* ---- p1 ---- */                                                     \
        if (NX) asm volatile("s_waitcnt vmcnt(4)" ::: "memory");               \
        if (S2) STAGE_AH((T) + 2, 0, BC)                                       \
        __builtin_amdgcn_sched_barrier(0);                                     \
        __builtin_amdgcn_s_setprio(1);                                         \
        QUAD(aR0, bC1, 0, 2)                                                   \
        __builtin_amdgcn_s_setprio(0);                                         \
        PHASE_END                                                              \
        /* ---- p2 ---- */                                                     \
        if (NX) asm volatile("s_waitcnt vmcnt(" P2W ")" ::: "memory");         \
        if (NX) {                                                              \
            _Pragma("unroll") for (int _i = 0; _i < 4; ++_i) {                 \
                aR0[_i][0] = LDA(_i, 0, BN);                                   \
                aR0[_i][1] = LDA(_i, 1, BN);                                   \
            }                                                                  \
        }                                                                      \
        if (S2) STAGE_AH((T) + 2, 1, BC)                                       \
        __builtin_amdgcn_sched_barrier(0);                                     \
        __builtin_amdgcn_s_setprio(1);                                         \
        QUAD(aR1, bC0, 4, 0)                                                   \
        __builtin_amdgcn_s_setprio(0);                                         \
        PHASE_END                                                              \
        /* ---- p3 ---- */                                                     \
        if (NX) {                                                              \
            _Pragma("unroll") for (int _j = 0; _j < 2; ++_j) {                 \
                bC0[_j][0] = LDB(_j, 0, BN);                                   \
                bC0[_j][1] = LDB(_j, 1, BN);                                   \
            }                                                                  \
        }                                                                      \
        if (S2) STAGE_BH((T) + 2, 0, BC)                                       \
        __builtin_amdgcn_sched_barrier(0);                                     \
        __builtin_amdgcn_s_setprio(1);                                         \
        QUAD(aR1, bC1, 4, 2)                                                   \
        __builtin_amdgcn_s_setprio(0);                                         \
        PHASE_END                                                              \
    }

    bf16x8 aR0[4][2], aR1[4][2], bC0[2][2], bC1[2][2];

    // prologue: tile0 fully + tile1 A-halves + Bh0(1); Bh1(1) staged at p0(0).
    STAGE_AH(0, 0, 0) STAGE_AH(0, 1, 0) STAGE_BH(0, 0, 0) STAGE_BH(0, 1, 0)
    STAGE_AH(1, 0, 1) STAGE_AH(1, 1, 1) STAGE_BH(1, 0, 1)
    asm volatile("s_waitcnt vmcnt(6)" ::: "memory");   // tile0's 8 retired
    __builtin_amdgcn_s_barrier();

#pragma unroll
    for (int i = 0; i < 4; ++i) {
        aR0[i][0] = LDA(i, 0, 0);
        aR0[i][1] = LDA(i, 1, 0);
    }
#pragma unroll
    for (int j = 0; j < 2; ++j) {
        bC0[j][0] = LDB(j, 0, 0);
        bC0[j][1] = LDB(j, 1, 0);
    }

    // main loop: tiles 0..13 (T+1, T+2 always exist -> no conditionals live).
    for (int T = 0; T < 14; ++T) {
        const int bc = T & 1, bn = bc ^ 1;
        KTILE(T, bc, bn, 1, 1, "2")
    }
    // epilogue: T=14 (no T+2 stage; vmcnt(0)@p2 covers Bh1(15)), T=15 (drain).
    KTILE(14, 0, 1, 0, 1, "0")
    KTILE(15, 1, 0, 0, 0, "0")

#undef KTILE
#undef PHASE_END
#undef STAGE_AH
#undef STAGE_BH
#undef LDA
#undef LDB
}

// ---------------------------------------------------------------------------
// QKV: grid=768 1-D, XCD-bijective swizzle; decode mt(64) x ntl(12);
// ntl>>2: 0=q 1=k (both elu+1) 2=v. All bf16 out.
// ---------------------------------------------------------------------------
__global__ __launch_bounds__(512) void gemm_qkv_256(
    const __bf16* __restrict__ xb,
    const __bf16* __restrict__ wqt, const __bf16* __restrict__ wkt,
    const __bf16* __restrict__ wvt,
    const float* __restrict__ bq, const float* __restrict__ bk,
    const float* __restrict__ bv,
    __bf16* __restrict__ qfb, __bf16* __restrict__ kfb, __bf16* __restrict__ vb)
{
    f32x4 acc[8][4];
#pragma unroll
    for (int i = 0; i < 8; ++i)
#pragma unroll
        for (int j = 0; j < 4; ++j) acc[i][j] = (f32x4){0.f, 0.f, 0.f, 0.f};

    // XCD swizzle: 768 blocks, 8 XCDs, 96/XCD -> each XCD: 8 consecutive mt
    // x all 12 ntl (B-panels + 8 A-panels localized in that XCD's L2).
    const int o   = blockIdx.x;
    const int swz = (o & 7) * 96 + (o >> 3);
    const int mt  = swz / 12;
    const int ntl = swz - mt * 12;

    const int which = ntl >> 2;
    const int nbase = (ntl & 3) * 256;
    const int mbase = mt * 256;

    const __bf16* BT  = (which == 0) ? wqt : (which == 1) ? wkt : wvt;
    const float* bias = (which == 0) ? bq : (which == 1) ? bk : bv;
    __bf16* outp      = (which == 0) ? qfb : (which == 1) ? kfb : vb;
    const bool feat   = (which < 2);

    mfma256_core(xb, BT, mbase, nbase, acc);

    const int t = threadIdx.x, lane = t & 63, wid = t >> 6;
    const int wm = wid >> 2, wn = wid & 3;
    const int fr = lane & 15, fq = lane >> 4;

#pragma unroll
    for (int ri = 0; ri < 8; ++ri)
#pragma unroll
        for (int cj = 0; cj < 4; ++cj) {
            const int col = nbase + wn * 64 + cj * 16 + fr;
            const float bval = bias[col];
#pragma unroll
            for (int r = 0; r < 4; ++r) {
                const int row = mbase + wm * 128 + ri * 16 + fq * 4 + r;
                float vv = acc[ri][cj][r] + bval;
                if (feat) vv = (vv > 0.f) ? (vv + 1.f) : __expf(vv);
                outp[(size_t)row * 1024 + col] = (__bf16)vv;
            }
        }
}

// ---------------------------------------------------------------------------
// out = y @ WoT + bo (fp32). grid=256 1-D, XCD swizzle.
// ---------------------------------------------------------------------------
__global__ __launch_bounds__(512) void gemm_out_256(
    const __bf16* __restrict__ yb, const __bf16* __restrict__ wot,
    const float* __restrict__ bo, float* __restrict__ out)
{
    f32x4 acc[8][4];
#pragma unroll
    for (int i = 0; i < 8; ++i)
#pragma unroll
        for (int j = 0; j < 4; ++j) acc[i][j] = (f32x4){0.f, 0.f, 0.f, 0.f};

    const int o   = blockIdx.x;
    const int swz = (o & 7) * 32 + (o >> 3);
    const int mbase = (swz >> 2) * 256;
    const int nbase = (swz & 3) * 256;

    mfma256_core(yb, wot, mbase, nbase, acc);

    const int t = threadIdx.x, lane = t & 63, wid = t >> 6;
    const int wm = wid >> 2, wn = wid & 3;
    const int fr = lane & 15, fq = lane >> 4;

#pragma unroll
    for (int ri = 0; ri < 8; ++ri)
#pragma unroll
        for (int cj = 0; cj < 4; ++cj) {
            const int col = nbase + wn * 64 + cj * 16 + fr;
            const float bval = bo[col];
#pragma unroll
            for (int r = 0; r < 4; ++r) {
                const int row = mbase + wm * 128 + ri * 16 + fq * 4 + r;
                out[(size_t)row * 1024 + col] = acc[ri][cj][r] + bval;
            }
        }
}

// ---------------------------------------------------------------------------
// kv partials: kvp[bh][chunk][m][d] = sum_{s in chunk} v[s][m]*kf[s][d]
// ksum partials via ones-A MFMA.  grid=(64 bh, 16 chunks of 256 s).
// ---------------------------------------------------------------------------
__global__ __launch_bounds__(256) void kv_ksum_mfma(
    const __bf16* __restrict__ kfb, const __bf16* __restrict__ vb,
    float* __restrict__ kvp, float* __restrict__ ksp)
{
    __shared__ __bf16 kfs[64 * 66];
    __shared__ __bf16 vs[64 * 66];

    const int bh = blockIdx.x;
    const int n = bh >> 4, h = bh & 15;
    const int chunk = blockIdx.y;
    const int t = threadIdx.x, lane = t & 63, w = t >> 6;
    const int fr = lane & 15, fq = lane >> 4;

    f32x4 acc[4];
#pragma unroll
    for (int j = 0; j < 4; j++) acc[j] = (f32x4){0.f, 0.f, 0.f, 0.f};
    f32x4 accks = (f32x4){0.f, 0.f, 0.f, 0.f};

    bf16x8 ones;
#pragma unroll
    for (int e = 0; e < 8; e++) ones[e] = (__bf16)1.0f;

    const size_t base = ((size_t)n * 4096 + (size_t)chunk * 256) * 1024 + h * 64;

    for (int tile = 0; tile < 4; tile++) {
#pragma unroll
        for (int i = 0; i < 2; i++) {
            int idx = t + i * 256;              // 0..511
            int s = idx >> 3, d0 = (idx & 7) * 8;
            bf16x8 k8 = *(const bf16x8*)(kfb + base + (size_t)(tile * 64 + s) * 1024 + d0);
            bf16x8 v8 = *(const bf16x8*)(vb  + base + (size_t)(tile * 64 + s) * 1024 + d0);
#pragma unroll
            for (int e = 0; e < 4; e++) {
                *(bf16x2*)(kfs + s * 66 + d0 + 2 * e) = (bf16x2){k8[2*e], k8[2*e+1]};
                *(bf16x2*)(vs  + s * 66 + d0 + 2 * e) = (bf16x2){v8[2*e], v8[2*e+1]};
            }
        }
        __syncthreads();

#pragma unroll
        for (int kk = 0; kk < 2; kk++) {
            bf16x8 af, bfr[4];
#pragma unroll
            for (int j = 0; j < 8; j++)
                af[j] = vs[(kk * 32 + fq * 8 + j) * 66 + 16 * w + fr];
#pragma unroll
            for (int j2 = 0; j2 < 4; j2++)
#pragma unroll
                for (int j = 0; j < 8; j++)
                    bfr[j2][j] = kfs[(kk * 32 + fq * 8 + j) * 66 + 16 * j2 + fr];
#pragma unroll
            for (int j2 = 0; j2 < 4; j2++)
                acc[j2] = __builtin_amdgcn_mfma_f32_16x16x32_bf16(
                    af, bfr[j2], acc[j2], 0, 0, 0);
            accks = __builtin_amdgcn_mfma_f32_16x16x32_bf16(
                ones, bfr[w], accks, 0, 0, 0);
        }
        __syncthreads();
    }

    const size_t pbase = ((size_t)bh * 16 + chunk) * 4096;
#pragma unroll
    for (int j2 = 0; j2 < 4; j2++)
#pragma unroll
        for (int r = 0; r < 4; r++) {
            int m = 16 * w + fq * 4 + r;
            int d = 16 * j2 + fr;
            kvp[pbase + m * 64 + d] = acc[j2][r];
        }
    if (fq == 0)
        ksp[((size_t)bh * 16 + chunk) * 64 + 16 * w + fr] = accks[0];
}

// ---------------------------------------------------------------------------
// reduce partials -> kvb bf16 [bh][m][d], ksumb bf16 [bh][d]
// ---------------------------------------------------------------------------
__global__ __launch_bounds__(256) void reduce_kv(
    const float* __restrict__ kvp, const float* __restrict__ ksp,
    __bf16* __restrict__ kvb, __bf16* __restrict__ ksumb)
{
    const int b = blockIdx.x;
    if (b < 1024) {
        int i = b * 256 + threadIdx.x;          // 0..262143
        int bh = i >> 12, md = i & 4095;
        float s = 0.f;
#pragma unroll
        for (int c = 0; c < 16; c++) s += kvp[((size_t)bh * 16 + c) * 4096 + md];
        kvb[i] = (__bf16)s;
    } else {
        int j = (b - 1024) * 256 + threadIdx.x; // 0..4095
        int bh = j >> 6, d = j & 63;
        float s = 0.f;
#pragma unroll
        for (int c = 0; c < 16; c++) s += ksp[((size_t)bh * 16 + c) * 64 + d];
        ksumb[j] = (__bf16)s;
    }
}

// ---------------------------------------------------------------------------
// y[g,h,m] = z * sum_d qf[g,h,d]*kv[bh,m,d], z = 1/(qf.ksum+eps)
// grid=(128 gtiles of 128, 16 h)
// ---------------------------------------------------------------------------
__global__ __launch_bounds__(256) void y_mfma(
    const __bf16* __restrict__ qfb, const __bf16* __restrict__ kvb,
    const __bf16* __restrict__ ksumb, __bf16* __restrict__ yb)
{
    __shared__ __bf16 qs[128 * 72];
    __shared__ __bf16 kvs[64 * 72];

    const int gbase = blockIdx.x * 128;
    const int h = blockIdx.y;
    const int bh = (gbase >> 12) * 16 + h;
    const int t = threadIdx.x, lane = t & 63, w = t >> 6;
    const int fr = lane & 15, fq = lane >> 4;

#pragma unroll
    for (int i = 0; i < 4; i++) {
        int idx = t + i * 256;                  // 0..1023
        int l = idx >> 3, d0 = (idx & 7) * 8;
        *(bf16x8*)(qs + l * 72 + d0) =
            *(const bf16x8*)(qfb + (size_t)(gbase + l) * 1024 + h * 64 + d0);
    }
#pragma unroll
    for (int i = 0; i < 2; i++) {
        int idx = t + i * 256;                  // 0..511
        int m = idx >> 3, d0 = (idx & 7) * 8;
        *(bf16x8*)(kvs + m * 72 + d0) =
            *(const bf16x8*)(kvb + (size_t)bh * 4096 + m * 64 + d0);
    }
    bf16x8 ksb[2];
#pragma unroll
    for (int kk = 0; kk < 2; kk++)
        ksb[kk] = *(const bf16x8*)(ksumb + bh * 64 + kk * 32 + fq * 8);
    __syncthreads();

    f32x4 acc[2][4], accz[2];
#pragma unroll
    for (int i = 0; i < 2; i++) {
        accz[i] = (f32x4){0.f, 0.f, 0.f, 0.f};
#pragma unroll
        for (int j = 0; j < 4; j++) acc[i][j] = (f32x4){0.f, 0.f, 0.f, 0.f};
    }

#pragma unroll
    for (int kk = 0; kk < 2; kk++) {
        bf16x8 af[2], bfr[4];
#pragma unroll
        for (int i = 0; i < 2; i++)
            af[i] = *(const bf16x8*)(qs + (32 * w + 16 * i + fr) * 72 + kk * 32 + fq * 8);
#pragma unroll
        for (int j = 0; j < 4; j++)
            bfr[j] = *(const bf16x8*)(kvs + (16 * j + fr) * 72 + kk * 32 + fq * 8);
#pragma unroll
        for (int i = 0; i < 2; i++) {
#pragma unroll
            for (int j = 0; j < 4; j++)
                acc[i][j] = __builtin_amdgcn_mfma_f32_16x16x32_bf16(
                    af[i], bfr[j], acc[i][j], 0, 0, 0);
            accz[i] = __builtin_amdgcn_mfma_f32_16x16x32_bf16(
                af[i], ksb[kk], accz[i], 0, 0, 0);
        }
    }

#pragma unroll
    for (int i = 0; i < 2; i++)
#pragma unroll
        for (int r = 0; r < 4; r++) {
            const float z = 1.0f / (accz[i][r] + 1e-6f);
            const int g = gbase + 32 * w + 16 * i + fq * 4 + r;
#pragma unroll
            for (int j = 0; j < 4; j++)
                yb[(size_t)g * 1024 + h * 64 + 16 * j + fr] =
                    (__bf16)(acc[i][j][r] * z);
        }
}

// ---------------------------------------------------------------------------
// prep: blocks 0..8191 = cast x->bf16; blocks 8192..12287 = transpose weights.
// ---------------------------------------------------------------------------
__global__ __launch_bounds__(256) void prep(
    const float* __restrict__ x, __bf16* __restrict__ xb,
    const float* __restrict__ w0, const float* __restrict__ w1,
    const float* __restrict__ w2, const float* __restrict__ w3,
    __bf16* __restrict__ o0, __bf16* __restrict__ o1,
    __bf16* __restrict__ o2, __bf16* __restrict__ o3)
{
    __shared__ float ld[32][33];
    const int b = blockIdx.x;
    const int t = threadIdx.x;

    if (b < 8192) {
        const size_t i = ((size_t)b * 256 + t) * 8;
        float4 a = *(const float4*)(x + i);
        float4 c = *(const float4*)(x + i + 4);
        bf16x8 o;
        o[0] = (__bf16)a.x; o[1] = (__bf16)a.y; o[2] = (__bf16)a.z; o[3] = (__bf16)a.w;
        o[4] = (__bf16)c.x; o[5] = (__bf16)c.y; o[6] = (__bf16)c.z; o[7] = (__bf16)c.w;
        *(bf16x8*)(xb + i) = o;
        return;
    }

    const int idx  = b - 8192;                  // 0..4095
    const int wsel = idx >> 10;                 // 0..3
    const int yy   = (idx >> 5) & 31;           // nbase/32
    const int xx   = idx & 31;                  // kbase/32
    const float* src = (wsel == 0) ? w0 : (wsel == 1) ? w1 : (wsel == 2) ? w2 : w3;
    __bf16* dst      = (wsel == 0) ? o0 : (wsel == 1) ? o1 : (wsel == 2) ? o2 : o3;

    const int kbase = xx * 32;
    const int nbase = yy * 32;
    const int r = t >> 3, c4 = (t & 7) * 4;

    float4 a = *(const float4*)(src + (size_t)(kbase + r) * 1024 + nbase + c4);
    ld[r][c4 + 0] = a.x; ld[r][c4 + 1] = a.y; ld[r][c4 + 2] = a.z; ld[r][c4 + 3] = a.w;
    __syncthreads();

    bf16x4 o;
    o[0] = (__bf16)ld[c4 + 0][r];
    o[1] = (__bf16)ld[c4 + 1][r];
    o[2] = (__bf16)ld[c4 + 2][r];
    o[3] = (__bf16)ld[c4 + 3][r];
    *(bf16x4*)(dst + (size_t)(nbase + r) * 1024 + kbase + c4) = o;
}

extern "C" void kernel_launch(void* const* d_in, const int* in_sizes, int n_in,
                              void* d_out, int out_size, void* d_ws, size_t ws_size,
                              hipStream_t stream)
{
    const float* x  = (const float*)d_in[0];
    const float* Wq = (const float*)d_in[1];
    const float* bq = (const float*)d_in[2];
    const float* Wk = (const float*)d_in[3];
    const float* bk = (const float*)d_in[4];
    const float* Wv = (const float*)d_in[5];
    const float* bv = (const float*)d_in[6];
    const float* Wo = (const float*)d_in[7];
    const float* bo = (const float*)d_in[8];
    float* out = (float*)d_out;

    __bf16* xb    = (__bf16*)d_ws;                   // 16777216
    __bf16* wqt   = xb + (size_t)16777216;           // 1048576 each
    __bf16* wkt   = wqt + 1048576;
    __bf16* wvt   = wkt + 1048576;
    __bf16* wot   = wvt + 1048576;
    __bf16* qfb   = wot + 1048576;                   // 16777216
    __bf16* kfb   = qfb + (size_t)16777216;          // 16777216 (reused as yb)
    __bf16* vb    = kfb + (size_t)16777216;          // 16777216
    float*  kvp   = (float*)(vb + (size_t)16777216); // 4194304 fp32 (16 MB)
    float*  ksp   = kvp + 4194304;                   // 65536 fp32
    __bf16* kvb   = (__bf16*)(ksp + 65536);          // 262144
    __bf16* ksumb = kvb + 262144;                    // 4096

    const int LDS_BYTES = 131072;
    (void)hipFuncSetAttribute((const void*)gemm_qkv_256,
                              hipFuncAttributeMaxDynamicSharedMemorySize, LDS_BYTES);
    (void)hipFuncSetAttribute((const void*)gemm_out_256,
                              hipFuncAttributeMaxDynamicSharedMemorySize, LDS_BYTES);

    prep<<<dim3(12288), dim3(256), 0, stream>>>(
        x, xb, Wq, Wk, Wv, Wo, wqt, wkt, wvt, wot);

    gemm_qkv_256<<<dim3(768), dim3(512), LDS_BYTES, stream>>>(
        xb, wqt, wkt, wvt, bq, bk, bv, qfb, kfb, vb);
    kv_ksum_mfma<<<dim3(64, 16), dim3(256), 0, stream>>>(kfb, vb, kvp, ksp);
    reduce_kv<<<dim3(1040), dim3(256), 0, stream>>>(kvp, ksp, kvb, ksumb);
    y_mfma<<<dim3(128, 16), dim3(256), 0, stream>>>(qfb, kvb, ksumb, kfb);
    gemm_out_256<<<dim3(256), dim3(512), LDS_BYTES, stream>>>(kfb, wot, bo, out);
}